// Round 12
// baseline (443.676 us; speedup 1.0000x reference)
//
#include <hip/hip_runtime.h>
#include <math.h>

// MHA fwd: B=8 H=16 T=1024 D=1024 dh=64. fp32 in/out, bf16 MFMA compute.
// Split-bf16 (hi+lo) 3-term MFMA for x@Wq, x@Wk and Q@K^T (logits sigma~1024
// need ~fp32 accuracy; 2-term and int8 variants fail the error budget).
// R1: S^T = K.Q^T (softmax in-lane). R2: frag-major panels + XCD swizzle.
// R3: V frag layout fused into V-GEMM epilogue. R4 FAILED: spill.
// R5: 64-key S chunking. R6: attn dbuf staging.
// R7: gemm_qk 256x256 / 8-wave / 4-phase counted-vmcnt. 125->112.5us, 911 TF.
// R8/R9 FAILED: schedule variants. R10/R11 NEUTRAL. gemm_qk at ceiling.
// R12/R15 REGRESSED/neutral, R16 best-so-far (331.4) but bt inference says
//     bt still ~59us each - THREE structures all ~55-60 by subtraction.
//     Either bt has an exotic bound none of 3 rewrites touched, or the
//     budget inference is wrong and ~45-90us hides in split/xpose/gaps.
// R14 DIAGNOSTIC: attn = 78.6us (3x differencing).
// R17 DIAGNOSTIC: triplicate bt<2> and bt<0> (both idempotent in order).
//     dT = 2*(bt2+bt0). dT~230 => bt slow confirmed (attack staging path);
//     dT~100 => bt~25, hole in split/xpose; dT~55 => R16 worked, hole is
//     launch overhead => fuse kernels. Reverted next round.

typedef unsigned short u16;
typedef unsigned int u32;
typedef __bf16  bf16x8 __attribute__((ext_vector_type(8)));
typedef unsigned short u16x8 __attribute__((ext_vector_type(8)));
typedef unsigned short u16x4 __attribute__((ext_vector_type(4)));
typedef short s16x4 __attribute__((ext_vector_type(4)));
typedef unsigned int u32x2 __attribute__((ext_vector_type(2)));
typedef float f32x4 __attribute__((ext_vector_type(4)));

#define MFMA16(a,b,c) __builtin_amdgcn_mfma_f32_16x16x32_bf16((a),(b),(c),0,0,0)
#define MFMA16K16(a,b,c) __builtin_amdgcn_mfma_f32_16x16x16bf16_1k((a),(b),(c),0,0,0)

static __device__ __forceinline__ u16 f2b(float f){
  unsigned u = __builtin_bit_cast(unsigned, f);
  u += 0x7fffu + ((u >> 16) & 1u);            // RNE
  return (u16)(u >> 16);
}
static __device__ __forceinline__ float b2f(u16 h){
  unsigned u = ((unsigned)h) << 16;
  return __builtin_bit_cast(float, u);
}
static __device__ __forceinline__ bf16x8 ldsfrag(const u16* p){
  return __builtin_bit_cast(bf16x8, *(const u16x8*)p);
}
static __device__ __forceinline__ u32 packhi(float fa, float fb){
  return __builtin_amdgcn_perm(__builtin_bit_cast(u32, fa),
                               __builtin_bit_cast(u32, fb), 0x07060302u);
}
static __device__ __forceinline__ void gld16(const void* g, void* l){
  __builtin_amdgcn_global_load_lds(
      (const __attribute__((address_space(1))) void*)g,
      (__attribute__((address_space(3))) void*)l, 16, 0, 0);
}

// Frag-major panel conventions (u16 index), bh = b*16+h, tt = t&1023, d in [0,64):
//  K (A-frag of 16x16x32):  ktile=tt>>7 fkt=(tt>>4)&7 l15=tt&15 | kc=d>>5 q=(d>>3)&3 j=d&7
//    idx = (((bh*8+ktile)*8+fkt)*2+kc)*512 + (q*16+l15)*8 + j          [16KB/ktile]
//  Q (B-frag of 16x16x32):  qtile=tt>>7 r=tt&127 wv=r>>5 mt=(r>>4)&1 l15=tt&15
//    idx = ((((bh*8+qtile)*4+wv)*2+mt)*2+kc)*512 + (q*16+l15)*8 + j    [16KB/qtile]
//  V (B-frag of 16x16x16):  ktile=tt>>7 fkt=(tt>>4)&7 q=(tt>>2)&3 j=tt&3 | nd=d>>4 l15=d&15
//    idx = ((((bh*8+ktile)*8+fkt)*4+nd)*64 + q*16+l15)*4 + j           [16KB/ktile]
// 64-key granularity: tile j (0..15) of a bh = contiguous 4096-u16 block at
//   panel_base(bh) + j*4096 in each of K/Kl/V panels.

// ---------------- split x (fp32 -> hi/lo bf16) ----------------
__global__ __launch_bounds__(256) void split_x_kernel(
    const float* __restrict__ x, u16* __restrict__ xh, u16* __restrict__ xl, int n)
{
  int i = (blockIdx.x * 256 + threadIdx.x) * 8;
  if (i >= n) return;
  float4 v0 = *(const float4*)(x + i);
  float4 v1 = *(const float4*)(x + i + 4);
  float vv[8] = {v0.x, v0.y, v0.z, v0.w, v1.x, v1.y, v1.z, v1.w};
  u16x8 hv, lv;
#pragma unroll
  for (int j = 0; j < 8; j++){
    u16 hb = f2b(vv[j]);
    hv[j] = hb;
    lv[j] = f2b(vv[j] - b2f(hb));
  }
  *(u16x8*)(xh + i) = hv;
  *(u16x8*)(xl + i) = lv;
}

// ---------------- fused transpose of all 4 weights (z selects matrix) --------
__global__ __launch_bounds__(256) void transpose4_kernel(
    const float* __restrict__ Wq, const float* __restrict__ Wk,
    const float* __restrict__ Wv, const float* __restrict__ Wp,
    u16* __restrict__ qh_, u16* __restrict__ ql_,
    u16* __restrict__ kh_, u16* __restrict__ kl_,
    u16* __restrict__ vt_, u16* __restrict__ pt_)
{
  __shared__ float t[32][33];
  const int z = blockIdx.z;
  const float* W = (z == 0) ? Wq : (z == 1) ? Wk : (z == 2) ? Wv : Wp;
  u16* Th = (z == 0) ? qh_ : (z == 1) ? kh_ : (z == 2) ? vt_ : pt_;
  u16* Tl = (z == 0) ? ql_ : (z == 1) ? kl_ : nullptr;
  int n0 = blockIdx.x * 32, k0 = blockIdx.y * 32;
  int tx = threadIdx.x, ty = threadIdx.y;
#pragma unroll
  for (int i = 0; i < 4; i++){
    int k = k0 + ty + i * 8;
    t[ty + i * 8][tx] = W[(size_t)k * 1024 + n0 + tx];
  }
  __syncthreads();
#pragma unroll
  for (int i = 0; i < 4; i++){
    int n = n0 + ty + i * 8;
    float v = t[tx][ty + i * 8];
    u16 h = f2b(v);
    Th[(size_t)n * 1024 + k0 + tx] = h;
    if (Tl) Tl[(size_t)n * 1024 + k0 + tx] = f2b(v - b2f(h));
  }
}

// ---------------- plain bf16 GEMM: C = A * Bt^T ----------------
// OUTMODE 0: fp32 row-major C[M][N].  OUTMODE 2: bf16 V-frag panels (N=1024).
// R16: 128x256 tile, grid (M/128, N/256) = 256 blocks = 1/CU. 8 waves:
// wm=wave>>2 (M half), wn=wave&3 (N quarter); wave owns 64x64 = 4x4 frags.
// BK=64 (2 kc-halves of 32). Frag-major LDS staged by permuted gld16 lanes.
// Per K-step, 2 phases {vmcnt(3); bar; rd 8 frags; stage 3; setprio mfma16}.
template<int OUTMODE>
__global__ __launch_bounds__(512, 2) void gemm_bt_kernel(
    const u16* __restrict__ A, const u16* __restrict__ Bt, void* __restrict__ Cv,
    int M, int N, int K)
{
  __shared__ __attribute__((aligned(16))) u16 sA[2][2][4096], sB[2][2][8192];
  const int tid = threadIdx.x, lane = tid & 63, wave = tid >> 6;
  const int quad = lane >> 4, l15 = lane & 15;
  const int wm = wave >> 2, wn = wave & 3;
  const int row0 = blockIdx.x * 128, col0 = blockIdx.y * 256;
  // staging sources (frag-major): A frag = wave; B frags = 2*wave, 2*wave+1
  const size_t abase  = (size_t)(row0 + wave * 16 + l15) * K + quad * 8;
  const size_t bbase0 = (size_t)(col0 + (2 * wave) * 16 + l15) * K + quad * 8;
  const size_t bbase1 = (size_t)(col0 + (2 * wave + 1) * 16 + l15) * K + quad * 8;
  (void)M;

  f32x4 acc[4][4];
#pragma unroll
  for (int mt = 0; mt < 4; mt++)
#pragma unroll
    for (int nt = 0; nt < 4; nt++) acc[mt][nt] = (f32x4)0.0f;

#define BT_STAGE(C, KK, NB) do {                                           \
    gld16(A  + abase  + (KK) + (C) * 32, &sA[NB][C][wave * 512]);          \
    gld16(Bt + bbase0 + (KK) + (C) * 32, &sB[NB][C][(2 * wave) * 512]);    \
    gld16(Bt + bbase1 + (KK) + (C) * 32, &sB[NB][C][(2 * wave + 1) * 512]);\
  } while (0)
#define BT_PHASE(C, BUF, KN, NB) do {                                      \
    asm volatile("s_waitcnt vmcnt(3)" ::: "memory");                       \
    asm volatile("s_barrier" ::: "memory");                                \
    bf16x8 a[4], b[4];                                                     \
    _Pragma("unroll")                                                      \
    for (int f = 0; f < 4; f++){                                           \
      a[f] = ldsfrag(&sA[BUF][C][(wm * 4 + f) * 512 + lane * 8]);          \
      b[f] = ldsfrag(&sB[BUF][C][(wn * 4 + f) * 512 + lane * 8]);          \
    }                                                                      \
    BT_STAGE(C, KN, NB);                                                   \
    __builtin_amdgcn_s_setprio(1);                                         \
    _Pragma("unroll")                                                      \
    for (int mt = 0; mt < 4; mt++)                                         \
      _Pragma("unroll")                                                    \
      for (int nt = 0; nt < 4; nt++)                                       \
        acc[mt][nt] = MFMA16(a[mt], b[nt], acc[mt][nt]);                   \
    __builtin_amdgcn_s_setprio(0);                                         \
  } while (0)

  const int NT = K >> 6;                 // BK = 64
  // prologue: step 0 into buf 0, group order kc0 then kc1
  BT_STAGE(0, 0, 0);
  BT_STAGE(1, 0, 0);

#pragma unroll 2
  for (int t = 0; t < NT; t++){
    const int buf = t & 1, nb = buf ^ 1;
    const int kn = ((t + 1) & (NT - 1)) * 64;   // wrap on last step
    BT_PHASE(0, buf, kn, nb);
    BT_PHASE(1, buf, kn, nb);
  }
  asm volatile("s_waitcnt vmcnt(0)" ::: "memory");  // drain wrap-prefetch

#undef BT_STAGE
#undef BT_PHASE

  if (OUTMODE == 2){
    // V-frag epilogue: j = r (contiguous) -> one u16x4 store per (mt,nt)
#pragma unroll
    for (int mt = 0; mt < 4; mt++)
#pragma unroll
      for (int nt = 0; nt < 4; nt++){
        int row = row0 + wm * 64 + mt * 16 + quad * 4;
        int col = col0 + wn * 64 + nt * 16 + l15;
        int bb = row >> 10, tt = row & 1023;
        int hh = (col >> 6) & 15, d = col & 63;
        int bhI = bb * 16 + hh;
        int ktile = tt >> 7, fkt = (tt >> 4) & 7, qF = (tt >> 2) & 3;
        int nd = d >> 4, l15F = d & 15;
        size_t idx = ((((size_t)(bhI * 8 + ktile) * 8 + fkt) * 4 + nd) * 64
                      + qF * 16 + l15F) * 4;
        u16x4 vals;
#pragma unroll
        for (int r = 0; r < 4; r++) vals[r] = f2b(acc[mt][nt][r]);
        *(u16x4*)(((u16*)Cv) + idx) = vals;
      }
  } else {
#pragma unroll
    for (int mt = 0; mt < 4; mt++)
#pragma unroll
      for (int nt = 0; nt < 4; nt++)
#pragma unroll
        for (int r = 0; r < 4; r++){
          int row = row0 + wm * 64 + mt * 16 + quad * 4 + r;
          int col = col0 + wn * 64 + nt * 16 + l15;
          ((float*)Cv)[(size_t)row * N + col] = acc[mt][nt][r];
        }
  }
}

// ---------------- 3-term split GEMM for Q||K projection -> frag-major panels ----
// R7 structure (best measured): 256x256 tile, 8 waves (wm=wave>>2 M, wn=wave&3
// N), wave owns 128x64 of C (8x4 frags). BK=32, LDS 128KB double-buffered,
// frag-major via pre-permuted gld16 lanes (lane-linear ds_read_b128, 0 confl).
// Phases per K-tile (quadrant order (0,0)(0,1)(1,1)(1,0)):
//   p0: vmcnt(4) bar | rdA0 rdB0 | issue G0(t+1) | mfma 24
//   p1: vmcnt(6) bar | rdB1      | issue G1(t+1) | mfma 24   (A regs reused)
//   p2: vmcnt(6) bar | rdA1      | issue G2(t+1) | mfma 24   (B regs reused)
//   p3:              | rdB0      |               | mfma 24   (no barrier)
// Last tile wrap-prefetches tile 0; post-loop vmcnt(0) drain.
__global__ __launch_bounds__(512, 2) void gemm_qk_kernel(
    const u16* __restrict__ Ah, const u16* __restrict__ Al,
    const u16* __restrict__ Bh, const u16* __restrict__ Bl,
    u16* __restrict__ Qhf, u16* __restrict__ Qlf,
    u16* __restrict__ Khf, u16* __restrict__ Klf, int M, int N, int K)
{
  __shared__ __attribute__((aligned(16))) u16 sA[2][2][8192], sB[2][2][8192];
  const int tid = threadIdx.x, lane = tid & 63, wave = tid >> 6;
  const int quad = lane >> 4, l15 = lane & 15;
  const int wm = wave >> 2, wn = wave & 3;
  const int row0 = blockIdx.x * 256, col0 = blockIdx.y * 256;
  const int f0a = (wave & 3) | ((wave & 4) << 1);   // A-half0 frags {0-3,8-11}
  const int f0b = (wave & 1) | ((wave >> 1) << 2);  // B-half0 frags {0,1,4,5,8,9,12,13}
  const size_t fstride = (size_t)16 * K;
  const size_t abase = (size_t)(row0 + l15) * K + quad * 8;
  const size_t bbase = (size_t)(col0 + l15) * K + quad * 8;
  (void)M; (void)N;

  f32x4 acc[8][4];
#pragma unroll
  for (int mt = 0; mt < 8; mt++)
#pragma unroll
    for (int nt = 0; nt < 4; nt++) acc[mt][nt] = (f32x4)0.0f;

#define STAGE_G0(KK, NB) do {                                              \
    gld16(Ah + abase + (size_t)f0a * fstride + (KK), &sA[NB][0][f0a * 512]); \
    gld16(Al + abase + (size_t)f0a * fstride + (KK), &sA[NB][1][f0a * 512]); \
    gld16(Bh + bbase + (size_t)f0b * fstride + (KK), &sB[NB][0][f0b * 512]); \
    gld16(Bl + bbase + (size_t)f0b * fstride + (KK), &sB[NB][1][f0b * 512]); \
  } while (0)
#define STAGE_G1(KK, NB) do {                                                        \
    gld16(Bh + bbase + (size_t)(f0b + 2) * fstride + (KK), &sB[NB][0][(f0b + 2) * 512]); \
    gld16(Bl + bbase + (size_t)(f0b + 2) * fstride + (KK), &sB[NB][1][(f0b + 2) * 512]); \
  } while (0)
#define STAGE_G2(KK, NB) do {                                                        \
    gld16(Ah + abase + (size_t)(f0a + 4) * fstride + (KK), &sA[NB][0][(f0a + 4) * 512]); \
    gld16(Al + abase + (size_t)(f0a + 4) * fstride + (KK), &sA[NB][1][(f0a + 4) * 512]); \
  } while (0)
#define RD_A(B4, BUF) do {                                        \
    _Pragma("unroll")                                             \
    for (int i = 0; i < 4; i++){                                  \
      int fa = wm * 8 + (B4) + i;                                 \
      ahf[i] = ldsfrag(&sA[BUF][0][fa * 512 + lane * 8]);         \
      alf[i] = ldsfrag(&sA[BUF][1][fa * 512 + lane * 8]);         \
    } } while (0)
#define RD_B(B2, BUF) do {                                        \
    _Pragma("unroll")                                             \
    for (int j = 0; j < 2; j++){                                  \
      int fb = wn * 4 + (B2) + j;                                 \
      bhf[j] = ldsfrag(&sB[BUF][0][fb * 512 + lane * 8]);         \
      blf[j] = ldsfrag(&sB[BUF][1][fb * 512 + lane * 8]);         \
    } } while (0)
#define MM(M0, N0) do {                                                      \
    __builtin_amdgcn_s_setprio(1);                                           \
    _Pragma("unroll")                                                        \
    for (int i = 0; i < 4; i++)                                              \
      _Pragma("unroll")                                                      \
      for (int j = 0; j < 2; j++){                                           \
        acc[(M0) + i][(N0) + j] = MFMA16(alf[i], bhf[j], acc[(M0) + i][(N0) + j]); \
        acc[(M0) + i][(N0) + j] = MFMA16(ahf[i], blf[j], acc[(M0) + i][(N0) + j]); \
        acc[(M0) + i][(N0) + j] = MFMA16(ahf[i], bhf[j], acc[(M0) + i][(N0) + j]); \
      }                                                                      \
    __builtin_amdgcn_s_setprio(0);                                           \
  } while (0)
#define VMCNT4() asm volatile("s_waitcnt vmcnt(4)" ::: "memory")
#define VMCNT6() asm volatile("s_waitcnt vmcnt(6)" ::: "memory")
#define BARRIER() asm volatile("s_barrier" ::: "memory")

  const int NT = K >> 5;
  STAGE_G0(0, 0);
  STAGE_G1(0, 0);
  STAGE_G2(0, 0);

  bf16x8 ahf[4], alf[4], bhf[2], blf[2];
#pragma unroll 2
  for (int t = 0; t < NT; t++){
    const int buf = t & 1, nb = buf ^ 1;
    const int kn = ((t + 1) & (NT - 1)) * 32;   // wrap on last tile
    VMCNT4();
    BARRIER();
    RD_A(0, buf);
    RD_B(0, buf);
    STAGE_G0(kn, nb);
    MM(0, 0);
    VMCNT6();
    BARRIER();
    RD_B(2, buf);
    STAGE_G1(kn, nb);
    MM(0, 2);
    VMCNT6();
    BARRIER();
    RD_A(4, buf);
    STAGE_G2(kn, nb);
    MM(4, 2);
    RD_B(0, buf);
    MM(4, 0);
  }
  asm volatile("s_waitcnt vmcnt(0)" ::: "memory");

#undef STAGE_G0
#undef STAGE_G1
#undef STAGE_G2
#undef RD_A
#undef RD_B
#undef MM
#undef VMCNT4
#undef VMCNT6
#undef BARRIER

  const bool isQ = (col0 < 1024);
#pragma unroll
  for (int mt = 0; mt < 8; mt++)
#pragma unroll
    for (int nt = 0; nt < 4; nt++)
#pragma unroll
      for (int r = 0; r < 4; r++){
        int row = row0 + wm * 128 + mt * 16 + quad * 4 + r;
        int col = col0 + wn * 64 + nt * 16 + l15;
        int bb = row >> 10, tt = row & 1023;
        int hh = (col >> 6) & 15, d = col & 63;
        int bhI = bb * 16 + hh;
        int kc = d >> 5, qF = (d >> 3) & 3, j = d & 7;
        float v = acc[mt][nt][r];
        u16 hi = f2b(v);
        u16 lo = f2b(v - b2f(hi));
        if (isQ){
          int qtile = tt >> 7, rr = tt & 127;
          int wv = rr >> 5, mtF = (rr >> 4) & 1, l15F = tt & 15;
          size_t idx = ((((size_t)(bhI * 8 + qtile) * 4 + wv) * 2 + mtF) * 2 + kc) * 512
                       + (qF * 16 + l15F) * 8 + j;
          Qhf[idx] = hi; Qlf[idx] = lo;
        } else {
          int ktile = tt >> 7, fkt = (tt >> 4) & 7, l15F = tt & 15;
          size_t idx = (((size_t)(bhI * 8 + ktile) * 8 + fkt) * 2 + kc) * 512
                       + (qF * 16 + l15F) * 8 + j;
          Khf[idx] = hi; Klf[idx] = lo;
        }
      }
}

// ---------------- flash attention (S^T, frag-major, 64-key dbuf tiles) -------
// R13 structure: grid = 512, block = 256 (4 waves). Block covers 256 q-rows
// (2 groups of 128). K/V frags re-read from LDS per group; s[] reused.
// launch_bounds(256,2): exactly 2 blocks/CU. setprio on MFMA clusters (T5).
// Measured via R14 differencing: ~78.6us.
__global__ __launch_bounds__(256, 2) void attn_kernel(
    const u16* __restrict__ Qhf, const u16* __restrict__ Qlf,
    const u16* __restrict__ Khf, const u16* __restrict__ Klf,
    const u16* __restrict__ Vf, u16* __restrict__ O)
{
  __shared__ __attribute__((aligned(16))) u16 lKh[2][4096], lKl[2][4096], lV[2][4096];
  const int tid = threadIdx.x, lane = tid & 63, wave = tid >> 6;
  const int quad = lane >> 4, l15 = lane & 15;
  const int qt = blockIdx.x >> 7, bh = blockIdx.x & 127;
  const int b = bh >> 4, h = bh & 15;
  const int q0 = qt * 256;
  const float BETA = 0.18033688011112042f;   // (1/sqrt(64)) * log2(e)

  bf16x8 qh[2][2][2], ql[2][2][2];           // [group][mt][kc]
  { // stage both groups' Q through the (not-yet-used) K buffers as scratch
    u16* sh = &lKh[0][0];  u16* sl = &lKl[0][0];   // flattened 2x4096 each
#pragma unroll
    for (int g = 0; g < 2; g++){
      size_t qbase = ((size_t)((bh * 8 + 2 * qt + g) * 4 + wave)) * 2048 + lane * 8;
#pragma unroll
      for (int i = 0; i < 4; i++){
        gld16(Qhf + qbase + i * 512, sh + wave * 2048 + i * 512);
        gld16(Qlf + qbase + i * 512, sl + wave * 2048 + i * 512);
      }
      __syncthreads();
#pragma unroll
      for (int mt = 0; mt < 2; mt++)
#pragma unroll
        for (int kc = 0; kc < 2; kc++){
          int off = wave * 2048 + (mt * 2 + kc) * 512 + lane * 8;
          qh[g][mt][kc] = ldsfrag(sh + off);
          ql[g][mt][kc] = ldsfrag(sl + off);
        }
      __syncthreads();
    }
  }

  float m_i[2][2] = {{-3.0e38f, -3.0e38f}, {-3.0e38f, -3.0e38f}};
  float l_i[2][2] = {{0.0f, 0.0f}, {0.0f, 0.0f}};
  f32x4 o_acc[2][2][4];
#pragma unroll
  for (int g = 0; g < 2; g++)
#pragma unroll
    for (int mt = 0; mt < 2; mt++)
#pragma unroll
      for (int nd = 0; nd < 4; nd++) o_acc[g][mt][nd] = (f32x4)0.0f;

  const size_t pan = (size_t)bh * 65536;   // per-bh K/Kl/V panel base (u16)
  // prefetch tile 0 into buf 0 (2 chunks per array per wave)
#pragma unroll
  for (int i = 0; i < 2; i++){
    int c = wave * 2 + i;                  // 0..7 chunks of 512 u16
    gld16(Khf + pan + c * 512 + lane * 8, &lKh[0][c * 512]);
    gld16(Klf + pan + c * 512 + lane * 8, &lKl[0][c * 512]);
    gld16(Vf  + pan + c * 512 + lane * 8, &lV [0][c * 512]);
  }

#pragma unroll 1
  for (int j = 0; j < 16; j++){
    const int cur = j & 1;
    __syncthreads();                       // drains tile-j loads (1 phase old)
    if (j < 15){
      size_t nb = pan + (size_t)(j + 1) * 4096;
      const int nxt = cur ^ 1;
#pragma unroll
      for (int i = 0; i < 2; i++){
        int c = wave * 2 + i;
        gld16(Khf + nb + c * 512 + lane * 8, &lKh[nxt][c * 512]);
        gld16(Klf + nb + c * 512 + lane * 8, &lKl[nxt][c * 512]);
        gld16(Vf  + nb + c * 512 + lane * 8, &lV [nxt][c * 512]);
      }
    }

#pragma unroll
    for (int g = 0; g < 2; g++){
      // S^T = K.Q^T for 64 keys (A = K frags, B = Q frags), 3-term split
      f32x4 s[2][4];
#pragma unroll
      for (int qt2 = 0; qt2 < 2; qt2++)
#pragma unroll
        for (int f4 = 0; f4 < 4; f4++) s[qt2][f4] = (f32x4)0.0f;
#pragma unroll
      for (int f4 = 0; f4 < 4; f4++){
        int aoff = f4 * 1024 + lane * 8;   // lane-linear, conflict-free
        bf16x8 kh0 = ldsfrag(&lKh[cur][aoff]);
        bf16x8 kh1 = ldsfrag(&lKh[cur][aoff + 512]);
        bf16x8 kl0 = ldsfrag(&lKl[cur][aoff]);
        bf16x8 kl1 = ldsfrag(&lKl[cur][aoff + 512]);
        __builtin_amdgcn_s_setprio(1);
#pragma unroll
        for (int qt2 = 0; qt2 < 2; qt2++){
          s[qt2][f4] = MFMA16(kl0, qh[g][qt2][0], s[qt2][f4]);
          s[qt2][f4] = MFMA16(kl1, qh[g][qt2][1], s[qt2][f4]);
          s[qt2][f4] = MFMA16(kh0, ql[g][qt2][0], s[qt2][f4]);
          s[qt2][f4] = MFMA16(kh1, ql[g][qt2][1], s[qt2][f4]);
          s[qt2][f4] = MFMA16(kh0, qh[g][qt2][0], s[qt2][f4]);
          s[qt2][f4] = MFMA16(kh1, qh[g][qt2][1], s[qt2][f4]);
        }
        __builtin_amdgcn_s_setprio(0);
      }

      // online softmax merge (lane l15 = q; 16 logits in-lane)
      float alpha[2];
#pragma unroll
      for (int qt2 = 0; qt2 < 2; qt2++){
        f32x4 mv = s[qt2][0];
#pragma unroll
        for (int f4 = 1; f4 < 4; f4++){
          mv[0] = fmaxf(mv[0], s[qt2][f4][0]); mv[1] = fmaxf(mv[1], s[qt2][f4][1]);
          mv[2] = fmaxf(mv[2], s[qt2][f4][2]); mv[3] = fmaxf(mv[3], s[qt2][f4][3]);
        }
        float mx = fmaxf(fmaxf(mv[0], mv[1]), fmaxf(mv[2], mv[3]));
        mx = fmaxf(mx, __shfl_xor(mx, 16));
        mx = fmaxf(mx, __shfl_xor(mx, 32));
        float mn = fmaxf(m_i[g][qt2], mx);
        alpha[qt2] = __builtin_amdgcn_exp2f((m_i[g][qt2] - mn) * BETA);
        m_i[g][qt2] = mn;
        float mb = mn * BETA;
        f32x4 ps = (f32x4)0.0f;
#pragma unroll
        for (int f4 = 0; f4 < 4; f4++)
#pragma unroll
          for (int r = 0; r < 4; r++){
            float p = __builtin_amdgcn_exp2f(s[qt2][f4][r] * BETA - mb);
            s[qt2][f4][r] = p;
            ps[r] += p;                    // 4 independent partial chains
          }
        float rs = (ps[0] + ps[1]) + (ps[2] + ps[3]);
        rs += __shfl_xor(rs, 16);
        rs += __shfl_xor(rs, 32);
        l_i[g][qt2] = l_i[g][qt2] * alpha[qt2] + rs;
      }

      // rescale O (alpha at lane l15=q -> broadcast to O row layout)
#pragma unroll
      for (int mt = 0; mt < 2; mt++)
#pragma unroll
        for (int r = 0; r < 4; r++){
          float ar = __shfl(alpha[mt], quad * 4 + r);
#pragma unroll
          for (int nd = 0; nd < 4; nd++) o_acc[g][mt][nd][r] *= ar;
        }

      // PV via 16x16x16 MFMA; P already in A-frag layout; V lane-linear b64
#pragma unroll
      for (int f4 = 0; f4 < 4; f4++){
        s16x4 vb[4];
#pragma unroll
        for (int nd = 0; nd < 4; nd++)
          vb[nd] = __builtin_bit_cast(s16x4,
                     *(const u16x4*)&lV[cur][(f4 * 4 + nd) * 256 + lane * 4]);
        __builtin_amdgcn_s_setprio(1);
#pragma unroll
        for (int qt2 = 0; qt2 < 2; qt2++){
          u32x2 pd;
          pd[0] = packhi(s[qt2][f4][1], s[qt2][f4][0]);
          pd[1] = packhi(s[qt2][f4][3], s[qt2][f4][2]);
          s16x4 pa = __builtin_bit_cast(s16x4, pd);
#pragma unroll
          for (int nd = 0; nd < 4; nd++)
            o_acc[g][qt2][nd] = MFMA16K16(pa, vb[nd], o_acc[g][qt2][nd]);
        }
        __builtin_amdgcn_s_setprio(0);
      }
    }
  }

#pragma unroll
  for (int g = 0; g < 2; g++)
#pragma unroll
    for (int mt = 0; mt < 2; mt++)
#pragma unroll
      for (int r = 0; r < 4; r++){
        float lr = __shfl(l_i[g][mt], quad * 4 + r);
        float inv = 1.0f / lr;
        int t = q0 + g * 128 + wave * 32 + mt * 16 + quad * 4 + r;
        size_t rowoff = (size_t)(b * 1024 + t) * 1024 + h * 64;
#pragma unroll
        for (int nd = 0; nd < 4; nd++)
          O[rowoff + nd * 16 + l15] = f2b(o_acc[g][mt][nd][r] * inv);
      }
}

// ---------------- launcher ----------------
extern "C" void kernel_launch(void* const* d_in, const int* in_sizes, int n_in,
                              void* d_out, int out_size, void* d_ws, size_t ws_size,
                              hipStream_t stream)
{
  const float* x  = (const float*)d_in[0];
  const float* Wq = (const float*)d_in[1];
  const float* Wk = (const float*)d_in[2];
  const float* Wv = (const float*)d_in[3];
  const float* Wp = (const float*)d_in[4];
  float* out = (float*)d_out;
  char* ws = (char*)d_ws;
  const size_t MB = 1024 * 1024;
  // workspace map (peak 124 MB):
  u16* xh   = (u16*)(ws + 0);        // 16MB; reused as O after V-GEMM
  u16* xl   = (u16*)(ws + 16 * MB);  // 16MB
  u16* wqkh = (u16*)(ws + 32 * MB);  // 4MB  [2048][1024]
  u16* wqkl = (u16*)(ws + 36 * MB);  // 4MB
  u16* wvt  = (u16*)(ws + 40 * MB);  // 2MB
  u16* wpt  = (u16*)(ws + 42 * MB);  // 2MB
  u16* Qhf  = (u16*)(ws + 44 * MB);  // 16MB frag-major Q hi
  u16* Qlf  = (u16*)(ws + 60 * MB);  // 16MB frag-major Q lo
  u16* Khf  = (u16*)(ws + 76 * MB);  // 16MB frag-major K hi
  u16* Klf  = (u16*)(ws + 92 * MB);  // 16MB frag-major K lo
  u16* Vf   = (u16*)(ws + 108 * MB); // 16MB frag-major V
  u16* obuf = xh;
  (void)in_sizes; (void)n_in; (void)out_size; (void)ws_size;

  split_x_kernel<<<4096, 256, 0, stream>>>(x, xh, xl, 8 * 1024 * 1024);
  transpose4_kernel<<<dim3(32, 32, 4), dim3(32, 8), 0, stream>>>(
      Wq, Wk, Wv, Wp, wqkh, wqkl, wqkh + 1024 * 1024, wqkl + 1024 * 1024, wvt, wpt);
  gemm_qk_kernel<<<dim3(32, 8), 512, 0, stream>>>(xh, xl, wqkh, wqkl,
                                                  Qhf, Qlf, Khf, Klf, 8192, 2048, 1024);
  // R17 DIAGNOSTIC: bt<2> is idempotent (reads xh,wvt; writes Vf). Run 3x.
  gemm_bt_kernel<2><<<dim3(64, 4), 512, 0, stream>>>(xh, wvt, (void*)Vf, 8192, 1024, 1024);
  gemm_bt_kernel<2><<<dim3(64, 4), 512, 0, stream>>>(xh, wvt, (void*)Vf, 8192, 1024, 1024);
  gemm_bt_kernel<2><<<dim3(64, 4), 512, 0, stream>>>(xh, wvt, (void*)Vf, 8192, 1024, 1024);
  attn_kernel<<<512, 256, 0, stream>>>(Qhf, Qlf, Khf, Klf, Vf, obuf);
  // R17 DIAGNOSTIC: bt<0> is idempotent (reads obuf,wpt; writes out). Run 3x.
  gemm_bt_kernel<0><<<dim3(64, 4), 512, 0, stream>>>(obuf, wpt, (void*)out, 8192, 1024, 1024);
  gemm_bt_kernel<0><<<dim3(64, 4), 512, 0, stream>>>(obuf, wpt, (void*)out, 8192, 1024, 1024);
  gemm_bt_kernel<0><<<dim3(64, 4), 512, 0, stream>>>(obuf, wpt, (void*)out, 8192, 1024, 1024);
}

// Round 13
// 319.766 us; speedup vs baseline: 1.3875x; 1.3875x over previous
//
#include <hip/hip_runtime.h>
#include <math.h>

// MHA fwd: B=8 H=16 T=1024 D=1024 dh=64. fp32 in/out, bf16 MFMA compute.
// Split-bf16 (hi+lo) 3-term MFMA for x@Wq, x@Wk and Q@K^T (logits sigma~1024
// need ~fp32 accuracy; 2-term and int8 variants fail the error budget).
// R1: S^T = K.Q^T (softmax in-lane). R2: frag-major panels + XCD swizzle.
// R3: V frag layout fused into V-GEMM epilogue.
// R7: gemm_qk 256x256 / 8-wave / 4-phase counted-vmcnt. 112.5us, 911 TF.
// R8-R11: schedule variants failed/neutral; gemm_qk at m97-struct ceiling.
// R13: attn 256-row blocks. R14: attn = 78.6us (differenced).
// R16: gemm_bt 128x256 / BK=64 / counted-vmcnt => 28us each (R17 differenced).
// R17 DIAGNOSTIC: budget = qk 112.5 + attn 78.6 + bt 56 + prep ~19 = 266
//     vs 331.4 total => ~65us hole = inter-kernel launch/drain overhead
//     (~10us x 6 launches, matches harness docs).
// R18: consolidate 6 -> 4 launches with zero-risk fusions:
//     prep_kernel = split_x + transpose4 (independent, role by bid);
//     qkbt_kernel = gemm_qk + V-GEMM (provably independent: qk reads
//     xh/xl/wqk, bt2 reads xh/wvt; disjoint outputs), bodies byte-identical,
//     one 128KB smem array (bt uses 96KB). attn and final bt<0> keep their
//     true dependencies as separate launches.

typedef unsigned short u16;
typedef unsigned int u32;
typedef __bf16  bf16x8 __attribute__((ext_vector_type(8)));
typedef unsigned short u16x8 __attribute__((ext_vector_type(8)));
typedef unsigned short u16x4 __attribute__((ext_vector_type(4)));
typedef short s16x4 __attribute__((ext_vector_type(4)));
typedef unsigned int u32x2 __attribute__((ext_vector_type(2)));
typedef float f32x4 __attribute__((ext_vector_type(4)));

#define MFMA16(a,b,c) __builtin_amdgcn_mfma_f32_16x16x32_bf16((a),(b),(c),0,0,0)
#define MFMA16K16(a,b,c) __builtin_amdgcn_mfma_f32_16x16x16bf16_1k((a),(b),(c),0,0,0)

static __device__ __forceinline__ u16 f2b(float f){
  unsigned u = __builtin_bit_cast(unsigned, f);
  u += 0x7fffu + ((u >> 16) & 1u);            // RNE
  return (u16)(u >> 16);
}
static __device__ __forceinline__ float b2f(u16 h){
  unsigned u = ((unsigned)h) << 16;
  return __builtin_bit_cast(float, u);
}
static __device__ __forceinline__ bf16x8 ldsfrag(const u16* p){
  return __builtin_bit_cast(bf16x8, *(const u16x8*)p);
}
static __device__ __forceinline__ u32 packhi(float fa, float fb){
  return __builtin_amdgcn_perm(__builtin_bit_cast(u32, fa),
                               __builtin_bit_cast(u32, fb), 0x07060302u);
}
static __device__ __forceinline__ void gld16(const void* g, void* l){
  __builtin_amdgcn_global_load_lds(
      (const __attribute__((address_space(1))) void*)g,
      (__attribute__((address_space(3))) void*)l, 16, 0, 0);
}

// Frag-major panel conventions (u16 index), bh = b*16+h, tt = t&1023, d in [0,64):
//  K (A-frag of 16x16x32):  ktile=tt>>7 fkt=(tt>>4)&7 l15=tt&15 | kc=d>>5 q=(d>>3)&3 j=d&7
//    idx = (((bh*8+ktile)*8+fkt)*2+kc)*512 + (q*16+l15)*8 + j          [16KB/ktile]
//  Q (B-frag of 16x16x32):  qtile=tt>>7 r=tt&127 wv=r>>5 mt=(r>>4)&1 l15=tt&15
//    idx = ((((bh*8+qtile)*4+wv)*2+mt)*2+kc)*512 + (q*16+l15)*8 + j    [16KB/qtile]
//  V (B-frag of 16x16x16):  ktile=tt>>7 fkt=(tt>>4)&7 q=(tt>>2)&3 j=tt&3 | nd=d>>4 l15=d&15
//    idx = ((((bh*8+ktile)*8+fkt)*4+nd)*64 + q*16+l15)*4 + j           [16KB/ktile]

// ---------------- fused prep: split x AND transpose 4 weights ----------------
// bid < 4096: split-x role (fp32 -> hi/lo bf16, 8 elems/thread).
// bid >= 4096: transpose role (b2 = bid-4096; z = b2>>10 selects matrix).
__global__ __launch_bounds__(256) void prep_kernel(
    const float* __restrict__ x, u16* __restrict__ xh, u16* __restrict__ xl,
    const float* __restrict__ Wq, const float* __restrict__ Wk,
    const float* __restrict__ Wv, const float* __restrict__ Wp,
    u16* __restrict__ qh_, u16* __restrict__ ql_,
    u16* __restrict__ kh_, u16* __restrict__ kl_,
    u16* __restrict__ vt_, u16* __restrict__ pt_)
{
  __shared__ float t[32][33];
  const int bid = blockIdx.x, tid = threadIdx.x;
  if (bid < 4096){
    int i = (bid * 256 + tid) * 8;               // covers exactly 8M elems
    float4 v0 = *(const float4*)(x + i);
    float4 v1 = *(const float4*)(x + i + 4);
    float vv[8] = {v0.x, v0.y, v0.z, v0.w, v1.x, v1.y, v1.z, v1.w};
    u16x8 hv, lv;
#pragma unroll
    for (int j = 0; j < 8; j++){
      u16 hb = f2b(vv[j]);
      hv[j] = hb;
      lv[j] = f2b(vv[j] - b2f(hb));
    }
    *(u16x8*)(xh + i) = hv;
    *(u16x8*)(xl + i) = lv;
    return;
  }
  const int b2 = bid - 4096;
  const int z = b2 >> 10, rem = b2 & 1023;
  const int n0 = (rem & 31) * 32, k0 = (rem >> 5) * 32;
  const int tx = tid & 31, ty = tid >> 5;
  const float* W = (z == 0) ? Wq : (z == 1) ? Wk : (z == 2) ? Wv : Wp;
  u16* Th = (z == 0) ? qh_ : (z == 1) ? kh_ : (z == 2) ? vt_ : pt_;
  u16* Tl = (z == 0) ? ql_ : (z == 1) ? kl_ : nullptr;
#pragma unroll
  for (int i = 0; i < 4; i++){
    int k = k0 + ty + i * 8;
    t[ty + i * 8][tx] = W[(size_t)k * 1024 + n0 + tx];
  }
  __syncthreads();
#pragma unroll
  for (int i = 0; i < 4; i++){
    int n = n0 + ty + i * 8;
    float v = t[tx][ty + i * 8];
    u16 h = f2b(v);
    Th[(size_t)n * 1024 + k0 + tx] = h;
    if (Tl) Tl[(size_t)n * 1024 + k0 + tx] = f2b(v - b2f(h));
  }
}

// ---------------- qk body (R7 structure, smem-pointer form) ----------------
// smem layout: qsA = smem (2buf x 2hl x 8192), qsB = smem + 32768. 128KB.
static __device__ __forceinline__ void qk_body(
    u16* smem, int bid,
    const u16* __restrict__ Ah, const u16* __restrict__ Al,
    const u16* __restrict__ Bh, const u16* __restrict__ Bl,
    u16* __restrict__ Qhf, u16* __restrict__ Qlf,
    u16* __restrict__ Khf, u16* __restrict__ Klf)
{
  const int K = 1024;
  const int tid = threadIdx.x, lane = tid & 63, wave = tid >> 6;
  const int quad = lane >> 4, l15 = lane & 15;
  const int wm = wave >> 2, wn = wave & 3;
  const int row0 = (bid & 31) * 256, col0 = (bid >> 5) * 256;
  const int f0a = (wave & 3) | ((wave & 4) << 1);   // A-half0 frags {0-3,8-11}
  const int f0b = (wave & 1) | ((wave >> 1) << 2);  // B-half0 frags
  const size_t fstride = (size_t)16 * K;
  const size_t abase = (size_t)(row0 + l15) * K + quad * 8;
  const size_t bbase = (size_t)(col0 + l15) * K + quad * 8;
  u16* const qsA = smem;            // [buf]*16384 + [hl]*8192 + off
  u16* const qsB = smem + 32768;

  f32x4 acc[8][4];
#pragma unroll
  for (int mt = 0; mt < 8; mt++)
#pragma unroll
    for (int nt = 0; nt < 4; nt++) acc[mt][nt] = (f32x4)0.0f;

#define QSA(NB, HL) (qsA + (NB) * 16384 + (HL) * 8192)
#define QSB(NB, HL) (qsB + (NB) * 16384 + (HL) * 8192)
#define STAGE_G0(KK, NB) do {                                                \
    gld16(Ah + abase + (size_t)f0a * fstride + (KK), QSA(NB,0) + f0a * 512); \
    gld16(Al + abase + (size_t)f0a * fstride + (KK), QSA(NB,1) + f0a * 512); \
    gld16(Bh + bbase + (size_t)f0b * fstride + (KK), QSB(NB,0) + f0b * 512); \
    gld16(Bl + bbase + (size_t)f0b * fstride + (KK), QSB(NB,1) + f0b * 512); \
  } while (0)
#define STAGE_G1(KK, NB) do {                                                          \
    gld16(Bh + bbase + (size_t)(f0b + 2) * fstride + (KK), QSB(NB,0) + (f0b + 2) * 512); \
    gld16(Bl + bbase + (size_t)(f0b + 2) * fstride + (KK), QSB(NB,1) + (f0b + 2) * 512); \
  } while (0)
#define STAGE_G2(KK, NB) do {                                                          \
    gld16(Ah + abase + (size_t)(f0a + 4) * fstride + (KK), QSA(NB,0) + (f0a + 4) * 512); \
    gld16(Al + abase + (size_t)(f0a + 4) * fstride + (KK), QSA(NB,1) + (f0a + 4) * 512); \
  } while (0)
#define RD_A(B4, BUF) do {                                        \
    _Pragma("unroll")                                             \
    for (int i = 0; i < 4; i++){                                  \
      int fa = wm * 8 + (B4) + i;                                 \
      ahf[i] = ldsfrag(QSA(BUF,0) + fa * 512 + lane * 8);         \
      alf[i] = ldsfrag(QSA(BUF,1) + fa * 512 + lane * 8);         \
    } } while (0)
#define RD_B(B2, BUF) do {                                        \
    _Pragma("unroll")                                             \
    for (int j = 0; j < 2; j++){                                  \
      int fb = wn * 4 + (B2) + j;                                 \
      bhf[j] = ldsfrag(QSB(BUF,0) + fb * 512 + lane * 8);         \
      blf[j] = ldsfrag(QSB(BUF,1) + fb * 512 + lane * 8);         \
    } } while (0)
#define MM(M0, N0) do {                                                      \
    __builtin_amdgcn_s_setprio(1);                                           \
    _Pragma("unroll")                                                        \
    for (int i = 0; i < 4; i++)                                              \
      _Pragma("unroll")                                                      \
      for (int j = 0; j < 2; j++){                                           \
        acc[(M0) + i][(N0) + j] = MFMA16(alf[i], bhf[j], acc[(M0) + i][(N0) + j]); \
        acc[(M0) + i][(N0) + j] = MFMA16(ahf[i], blf[j], acc[(M0) + i][(N0) + j]); \
        acc[(M0) + i][(N0) + j] = MFMA16(ahf[i], bhf[j], acc[(M0) + i][(N0) + j]); \
      }                                                                      \
    __builtin_amdgcn_s_setprio(0);                                           \
  } while (0)

  const int NT = K >> 5;
  STAGE_G0(0, 0);
  STAGE_G1(0, 0);
  STAGE_G2(0, 0);

  bf16x8 ahf[4], alf[4], bhf[2], blf[2];
#pragma unroll 2
  for (int t = 0; t < NT; t++){
    const int buf = t & 1, nb = buf ^ 1;
    const int kn = ((t + 1) & (NT - 1)) * 32;   // wrap on last tile
    asm volatile("s_waitcnt vmcnt(4)" ::: "memory");
    asm volatile("s_barrier" ::: "memory");
    RD_A(0, buf);
    RD_B(0, buf);
    STAGE_G0(kn, nb);
    MM(0, 0);
    asm volatile("s_waitcnt vmcnt(6)" ::: "memory");
    asm volatile("s_barrier" ::: "memory");
    RD_B(2, buf);
    STAGE_G1(kn, nb);
    MM(0, 2);
    asm volatile("s_waitcnt vmcnt(6)" ::: "memory");
    asm volatile("s_barrier" ::: "memory");
    RD_A(4, buf);
    STAGE_G2(kn, nb);
    MM(4, 2);
    RD_B(0, buf);
    MM(4, 0);
  }
  asm volatile("s_waitcnt vmcnt(0)" ::: "memory");

#undef QSA
#undef QSB
#undef STAGE_G0
#undef STAGE_G1
#undef STAGE_G2
#undef RD_A
#undef RD_B
#undef MM

  const bool isQ = (col0 < 1024);
#pragma unroll
  for (int mt = 0; mt < 8; mt++)
#pragma unroll
    for (int nt = 0; nt < 4; nt++)
#pragma unroll
      for (int r = 0; r < 4; r++){
        int row = row0 + wm * 128 + mt * 16 + quad * 4 + r;
        int col = col0 + wn * 64 + nt * 16 + l15;
        int bb = row >> 10, tt = row & 1023;
        int hh = (col >> 6) & 15, d = col & 63;
        int bhI = bb * 16 + hh;
        int kc = d >> 5, qF = (d >> 3) & 3, j = d & 7;
        float v = acc[mt][nt][r];
        u16 hi = f2b(v);
        u16 lo = f2b(v - b2f(hi));
        if (isQ){
          int qtile = tt >> 7, rr = tt & 127;
          int wv = rr >> 5, mtF = (rr >> 4) & 1, l15F = tt & 15;
          size_t idx = ((((size_t)(bhI * 8 + qtile) * 4 + wv) * 2 + mtF) * 2 + kc) * 512
                       + (qF * 16 + l15F) * 8 + j;
          Qhf[idx] = hi; Qlf[idx] = lo;
        } else {
          int ktile = tt >> 7, fkt = (tt >> 4) & 7, l15F = tt & 15;
          size_t idx = (((size_t)(bhI * 8 + ktile) * 8 + fkt) * 2 + kc) * 512
                       + (qF * 16 + l15F) * 8 + j;
          Khf[idx] = hi; Klf[idx] = lo;
        }
      }
}

// ---------------- V-GEMM body (R16 structure, smem-pointer form) -------------
// smem layout: bsA = smem (2buf x 2kc x 4096), bsB = smem + 16384
// (2buf x 2kc x 8192). 96KB of the 128KB block.
static __device__ __forceinline__ void bt2_body(
    u16* smem, int bid,
    const u16* __restrict__ A, const u16* __restrict__ Bt, u16* __restrict__ Cv)
{
  const int K = 1024;
  const int tid = threadIdx.x, lane = tid & 63, wave = tid >> 6;
  const int quad = lane >> 4, l15 = lane & 15;
  const int wm = wave >> 2, wn = wave & 3;
  const int row0 = (bid & 63) * 128, col0 = (bid >> 6) * 256;
  const size_t abase  = (size_t)(row0 + wave * 16 + l15) * K + quad * 8;
  const size_t bbase0 = (size_t)(col0 + (2 * wave) * 16 + l15) * K + quad * 8;
  const size_t bbase1 = (size_t)(col0 + (2 * wave + 1) * 16 + l15) * K + quad * 8;
  u16* const bsA = smem;            // [buf]*8192 + [kc]*4096 + off
  u16* const bsB = smem + 16384;    // [buf]*16384 + [kc]*8192 + off

  f32x4 acc[4][4];
#pragma unroll
  for (int mt = 0; mt < 4; mt++)
#pragma unroll
    for (int nt = 0; nt < 4; nt++) acc[mt][nt] = (f32x4)0.0f;

#define BT_STAGE(C, KK, NB) do {                                                      \
    gld16(A  + abase  + (KK) + (C) * 32, bsA + (NB) * 8192 + (C) * 4096 + wave * 512);\
    gld16(Bt + bbase0 + (KK) + (C) * 32, bsB + (NB) * 16384 + (C) * 8192 + (2 * wave) * 512); \
    gld16(Bt + bbase1 + (KK) + (C) * 32, bsB + (NB) * 16384 + (C) * 8192 + (2 * wave + 1) * 512); \
  } while (0)
#define BT_PHASE(C, BUF, KN, NB) do {                                      \
    asm volatile("s_waitcnt vmcnt(3)" ::: "memory");                       \
    asm volatile("s_barrier" ::: "memory");                                \
    bf16x8 a[4], b[4];                                                     \
    _Pragma("unroll")                                                      \
    for (int f = 0; f < 4; f++){                                           \
      a[f] = ldsfrag(bsA + (BUF) * 8192 + (C) * 4096 + (wm * 4 + f) * 512 + lane * 8); \
      b[f] = ldsfrag(bsB + (BUF) * 16384 + (C) * 8192 + (wn * 4 + f) * 512 + lane * 8); \
    }                                                                      \
    BT_STAGE(C, KN, NB);                                                   \
    __builtin_amdgcn_s_setprio(1);                                         \
    _Pragma("unroll")                                                      \
    for (int mt = 0; mt < 4; mt++)                                         \
      _Pragma("unroll")                                                    \
      for (int nt = 0; nt < 4; nt++)                                       \
        acc[mt][nt] = MFMA16(a[mt], b[nt], acc[mt][nt]);                   \
    __builtin_amdgcn_s_setprio(0);                                         \
  } while (0)

  const int NT = K >> 6;                 // BK = 64
  BT_STAGE(0, 0, 0);
  BT_STAGE(1, 0, 0);

#pragma unroll 2
  for (int t = 0; t < NT; t++){
    const int buf = t & 1, nb = buf ^ 1;
    const int kn = ((t + 1) & (NT - 1)) * 64;   // wrap on last step
    BT_PHASE(0, buf, kn, nb);
    BT_PHASE(1, buf, kn, nb);
  }
  asm volatile("s_waitcnt vmcnt(0)" ::: "memory");

#undef BT_STAGE
#undef BT_PHASE

  // V-frag epilogue: j = r (contiguous) -> one u16x4 store per (mt,nt)
#pragma unroll
  for (int mt = 0; mt < 4; mt++)
#pragma unroll
    for (int nt = 0; nt < 4; nt++){
      int row = row0 + wm * 64 + mt * 16 + quad * 4;
      int col = col0 + wn * 64 + nt * 16 + l15;
      int bb = row >> 10, tt = row & 1023;
      int hh = (col >> 6) & 15, d = col & 63;
      int bhI = bb * 16 + hh;
      int ktile = tt >> 7, fkt = (tt >> 4) & 7, qF = (tt >> 2) & 3;
      int nd = d >> 4, l15F = d & 15;
      size_t idx = ((((size_t)(bhI * 8 + ktile) * 8 + fkt) * 4 + nd) * 64
                    + qF * 16 + l15F) * 4;
      u16x4 vals;
#pragma unroll
      for (int r = 0; r < 4; r++) vals[r] = f2b(acc[mt][nt][r]);
      *(u16x4*)(Cv + idx) = vals;
    }
}

// ---------------- fused qk + V-GEMM launch (independent workloads) -----------
// blocks 0-255: gemm_qk tiles. blocks 256-511: V-GEMM tiles. Disjoint
// inputs/outputs; one 128KB smem region shared by role.
__global__ __launch_bounds__(512, 2) void qkbt_kernel(
    const u16* __restrict__ Ah, const u16* __restrict__ Al,
    const u16* __restrict__ Bh, const u16* __restrict__ Bl,
    u16* __restrict__ Qhf, u16* __restrict__ Qlf,
    u16* __restrict__ Khf, u16* __restrict__ Klf,
    const u16* __restrict__ Bt2, u16* __restrict__ Vf)
{
  __shared__ __attribute__((aligned(16))) u16 smem[65536];   // 128KB
  const int bid = blockIdx.x;
  if (bid < 256)
    qk_body(smem, bid, Ah, Al, Bh, Bl, Qhf, Qlf, Khf, Klf);
  else
    bt2_body(smem, bid - 256, Ah, Bt2, Vf);   // A = xh (hi panel only)
}

// ---------------- final projection GEMM: out = obuf * wpt^T (fp32 out) -------
// R16 structure: 128x256 tile, BK=64, counted vmcnt, frag-major staging.
__global__ __launch_bounds__(512, 2) void gemm_p_kernel(
    const u16* __restrict__ A, const u16* __restrict__ Bt, float* __restrict__ Cv)
{
  __shared__ __attribute__((aligned(16))) u16 sA[2][2][4096], sB[2][2][8192];
  const int K = 1024, N = 1024;
  const int tid = threadIdx.x, lane = tid & 63, wave = tid >> 6;
  const int quad = lane >> 4, l15 = lane & 15;
  const int wm = wave >> 2, wn = wave & 3;
  const int row0 = blockIdx.x * 128, col0 = blockIdx.y * 256;
  const size_t abase  = (size_t)(row0 + wave * 16 + l15) * K + quad * 8;
  const size_t bbase0 = (size_t)(col0 + (2 * wave) * 16 + l15) * K + quad * 8;
  const size_t bbase1 = (size_t)(col0 + (2 * wave + 1) * 16 + l15) * K + quad * 8;

  f32x4 acc[4][4];
#pragma unroll
  for (int mt = 0; mt < 4; mt++)
#pragma unroll
    for (int nt = 0; nt < 4; nt++) acc[mt][nt] = (f32x4)0.0f;

#define BT_STAGE(C, KK, NB) do {                                           \
    gld16(A  + abase  + (KK) + (C) * 32, &sA[NB][C][wave * 512]);          \
    gld16(Bt + bbase0 + (KK) + (C) * 32, &sB[NB][C][(2 * wave) * 512]);    \
    gld16(Bt + bbase1 + (KK) + (C) * 32, &sB[NB][C][(2 * wave + 1) * 512]);\
  } while (0)
#define BT_PHASE(C, BUF, KN, NB) do {                                      \
    asm volatile("s_waitcnt vmcnt(3)" ::: "memory");                       \
    asm volatile("s_barrier" ::: "memory");                                \
    bf16x8 a[4], b[4];                                                     \
    _Pragma("unroll")                                                      \
    for (int f = 0; f < 4; f++){                                           \
      a[f] = ldsfrag(&sA[BUF][C][(wm * 4 + f) * 512 + lane * 8]);          \
      b[f] = ldsfrag(&sB[BUF][C][(wn * 4 + f) * 512 + lane * 8]);          \
    }                                                                      \
    BT_STAGE(C, KN, NB);                                                   \
    __builtin_amdgcn_s_setprio(1);                                         \
    _Pragma("unroll")                                                      \
    for (int mt = 0; mt < 4; mt++)                                         \
      _Pragma("unroll")                                                    \
      for (int nt = 0; nt < 4; nt++)                                       \
        acc[mt][nt] = MFMA16(a[mt], b[nt], acc[mt][nt]);                   \
    __builtin_amdgcn_s_setprio(0);                                         \
  } while (0)

  const int NT = K >> 6;                 // BK = 64
  BT_STAGE(0, 0, 0);
  BT_STAGE(1, 0, 0);

#pragma unroll 2
  for (int t = 0; t < NT; t++){
    const int buf = t & 1, nb = buf ^ 1;
    const int kn = ((t + 1) & (NT - 1)) * 64;   // wrap on last step
    BT_PHASE(0, buf, kn, nb);
    BT_PHASE(1, buf, kn, nb);
  }
  asm volatile("s_waitcnt vmcnt(0)" ::: "memory");

#undef BT_STAGE
#undef BT_PHASE

#pragma unroll
  for (int mt = 0; mt < 4; mt++)
#pragma unroll
    for (int nt = 0; nt < 4; nt++)
#pragma unroll
      for (int r = 0; r < 4; r++){
        int row = row0 + wm * 64 + mt * 16 + quad * 4 + r;
        int col = col0 + wn * 64 + nt * 16 + l15;
        Cv[(size_t)row * N + col] = acc[mt][nt][r];
      }
}

// ---------------- flash attention (S^T, frag-major, 64-key dbuf tiles) -------
// R13 structure: grid = 512, block = 256 (4 waves). Block covers 256 q-rows
// (2 groups of 128). K/V frags re-read from LDS per group; s[] reused.
// launch_bounds(256,2): exactly 2 blocks/CU. setprio on MFMA clusters (T5).
// Measured via R14 differencing: ~78.6us.
__global__ __launch_bounds__(256, 2) void attn_kernel(
    const u16* __restrict__ Qhf, const u16* __restrict__ Qlf,
    const u16* __restrict__ Khf, const u16* __restrict__ Klf,
    const u16* __restrict__ Vf, u16* __restrict__ O)
{
  __shared__ __attribute__((aligned(16))) u16 lKh[2][4096], lKl[2][4096], lV[2][4096];
  const int tid = threadIdx.x, lane = tid & 63, wave = tid >> 6;
  const int quad = lane >> 4, l15 = lane & 15;
  const int qt = blockIdx.x >> 7, bh = blockIdx.x & 127;
  const int b = bh >> 4, h = bh & 15;
  const int q0 = qt * 256;
  const float BETA = 0.18033688011112042f;   // (1/sqrt(64)) * log2(e)

  bf16x8 qh[2][2][2], ql[2][2][2];           // [group][mt][kc]
  { // stage both groups' Q through the (not-yet-used) K buffers as scratch
    u16* sh = &lKh[0][0];  u16* sl = &lKl[0][0];   // flattened 2x4096 each
#pragma unroll
    for (int g = 0; g < 2; g++){
      size_t qbase = ((size_t)((bh * 8 + 2 * qt + g) * 4 + wave)) * 2048 + lane * 8;
#pragma unroll
      for (int i = 0; i < 4; i++){
        gld16(Qhf + qbase + i * 512, sh + wave * 2048 + i * 512);
        gld16(Qlf + qbase + i * 512, sl + wave * 2048 + i * 512);
      }
      __syncthreads();
#pragma unroll
      for (int mt = 0; mt < 2; mt++)
#pragma unroll
        for (int kc = 0; kc < 2; kc++){
          int off = wave * 2048 + (mt * 2 + kc) * 512 + lane * 8;
          qh[g][mt][kc] = ldsfrag(sh + off);
          ql[g][mt][kc] = ldsfrag(sl + off);
        }
      __syncthreads();
    }
  }

  float m_i[2][2] = {{-3.0e38f, -3.0e38f}, {-3.0e38f, -3.0e38f}};
  float l_i[2][2] = {{0.0f, 0.0f}, {0.0f, 0.0f}};
  f32x4 o_acc[2][2][4];
#pragma unroll
  for (int g = 0; g < 2; g++)
#pragma unroll
    for (int mt = 0; mt < 2; mt++)
#pragma unroll
      for (int nd = 0; nd < 4; nd++) o_acc[g][mt][nd] = (f32x4)0.0f;

  const size_t pan = (size_t)bh * 65536;   // per-bh K/Kl/V panel base (u16)
#pragma unroll
  for (int i = 0; i < 2; i++){
    int c = wave * 2 + i;                  // 0..7 chunks of 512 u16
    gld16(Khf + pan + c * 512 + lane * 8, &lKh[0][c * 512]);
    gld16(Klf + pan + c * 512 + lane * 8, &lKl[0][c * 512]);
    gld16(Vf  + pan + c * 512 + lane * 8, &lV [0][c * 512]);
  }

#pragma unroll 1
  for (int j = 0; j < 16; j++){
    const int cur = j & 1;
    __syncthreads();                       // drains tile-j loads (1 phase old)
    if (j < 15){
      size_t nb = pan + (size_t)(j + 1) * 4096;
      const int nxt = cur ^ 1;
#pragma unroll
      for (int i = 0; i < 2; i++){
        int c = wave * 2 + i;
        gld16(Khf + nb + c * 512 + lane * 8, &lKh[nxt][c * 512]);
        gld16(Klf + nb + c * 512 + lane * 8, &lKl[nxt][c * 512]);
        gld16(Vf  + nb + c * 512 + lane * 8, &lV [nxt][c * 512]);
      }
    }

#pragma unroll
    for (int g = 0; g < 2; g++){
      // S^T = K.Q^T for 64 keys (A = K frags, B = Q frags), 3-term split
      f32x4 s[2][4];
#pragma unroll
      for (int qt2 = 0; qt2 < 2; qt2++)
#pragma unroll
        for (int f4 = 0; f4 < 4; f4++) s[qt2][f4] = (f32x4)0.0f;
#pragma unroll
      for (int f4 = 0; f4 < 4; f4++){
        int aoff = f4 * 1024 + lane * 8;   // lane-linear, conflict-free
        bf16x8 kh0 = ldsfrag(&lKh[cur][aoff]);
        bf16x8 kh1 = ldsfrag(&lKh[cur][aoff + 512]);
        bf16x8 kl0 = ldsfrag(&lKl[cur][aoff]);
        bf16x8 kl1 = ldsfrag(&lKl[cur][aoff + 512]);
        __builtin_amdgcn_s_setprio(1);
#pragma unroll
        for (int qt2 = 0; qt2 < 2; qt2++){
          s[qt2][f4] = MFMA16(kl0, qh[g][qt2][0], s[qt2][f4]);
          s[qt2][f4] = MFMA16(kl1, qh[g][qt2][1], s[qt2][f4]);
          s[qt2][f4] = MFMA16(kh0, ql[g][qt2][0], s[qt2][f4]);
          s[qt2][f4] = MFMA16(kh1, ql[g][qt2][1], s[qt2][f4]);
          s[qt2][f4] = MFMA16(kh0, qh[g][qt2][0], s[qt2][f4]);
          s[qt2][f4] = MFMA16(kh1, qh[g][qt2][1], s[qt2][f4]);
        }
        __builtin_amdgcn_s_setprio(0);
      }

      // online softmax merge (lane l15 = q; 16 logits in-lane)
      float alpha[2];
#pragma unroll
      for (int qt2 = 0; qt2 < 2; qt2++){
        f32x4 mv = s[qt2][0];
#pragma unroll
        for (int f4 = 1; f4 < 4; f4++){
          mv[0] = fmaxf(mv[0], s[qt2][f4][0]); mv[1] = fmaxf(mv[1], s[qt2][f4][1]);
          mv[2] = fmaxf(mv[2], s[qt2][f4][2]); mv[3] = fmaxf(mv[3], s[qt2][f4][3]);
        }
        float mx = fmaxf(fmaxf(mv[0], mv[1]), fmaxf(mv[2], mv[3]));
        mx = fmaxf(mx, __shfl_xor(mx, 16));
        mx = fmaxf(mx, __shfl_xor(mx, 32));
        float mn = fmaxf(m_i[g][qt2], mx);
        alpha[qt2] = __builtin_amdgcn_exp2f((m_i[g][qt2] - mn) * BETA);
        m_i[g][qt2] = mn;
        float mb = mn * BETA;
        f32x4 ps = (f32x4)0.0f;
#pragma unroll
        for (int f4 = 0; f4 < 4; f4++)
#pragma unroll
          for (int r = 0; r < 4; r++){
            float p = __builtin_amdgcn_exp2f(s[qt2][f4][r] * BETA - mb);
            s[qt2][f4][r] = p;
            ps[r] += p;                    // 4 independent partial chains
          }
        float rs = (ps[0] + ps[1]) + (ps[2] + ps[3]);
        rs += __shfl_xor(rs, 16);
        rs += __shfl_xor(rs, 32);
        l_i[g][qt2] = l_i[g][qt2] * alpha[qt2] + rs;
      }

      // rescale O (alpha at lane l15=q -> broadcast to O row layout)
#pragma unroll
      for (int mt = 0; mt < 2; mt++)
#pragma unroll
        for (int r = 0; r < 4; r++){
          float ar = __shfl(alpha[mt], quad * 4 + r);
#pragma unroll
          for (int nd = 0; nd < 4; nd++) o_acc[g][mt][nd][r] *= ar;
        }

      // PV via 16x16x16 MFMA; P already in A-frag layout; V lane-linear b64
#pragma unroll
      for (int f4 = 0; f4 < 4; f4++){
        s16x4 vb[4];
#pragma unroll
        for (int nd = 0; nd < 4; nd++)
          vb[nd] = __builtin_bit_cast(s16x4,
                     *(const u16x4*)&lV[cur][(f4 * 4 + nd) * 256 + lane * 4]);
        __builtin_amdgcn_s_setprio(1);
#pragma unroll
        for (int qt2 = 0; qt2 < 2; qt2++){
          u32x2 pd;
          pd[0] = packhi(s[qt2][f4][1], s[qt2][f4][0]);
          pd[1] = packhi(s[qt2][f4][3], s[qt2][f4][2]);
          s16x4 pa = __builtin_bit_cast(s16x4, pd);
#pragma unroll
          for (int nd = 0; nd < 4; nd++)
            o_acc[g][qt2][nd] = MFMA16K16(pa, vb[nd], o_acc[g][qt2][nd]);
        }
        __builtin_amdgcn_s_setprio(0);
      }
    }
  }

#pragma unroll
  for (int g = 0; g < 2; g++)
#pragma unroll
    for (int mt = 0; mt < 2; mt++)
#pragma unroll
      for (int r = 0; r < 4; r++){
        float lr = __shfl(l_i[g][mt], quad * 4 + r);
        float inv = 1.0f / lr;
        int t = q0 + g * 128 + wave * 32 + mt * 16 + quad * 4 + r;
        size_t rowoff = (size_t)(b * 1024 + t) * 1024 + h * 64;
#pragma unroll
        for (int nd = 0; nd < 4; nd++)
          O[rowoff + nd * 16 + l15] = f2b(o_acc[g][mt][nd][r] * inv);
      }
}

// ---------------- launcher ----------------
extern "C" void kernel_launch(void* const* d_in, const int* in_sizes, int n_in,
                              void* d_out, int out_size, void* d_ws, size_t ws_size,
                              hipStream_t stream)
{
  const float* x  = (const float*)d_in[0];
  const float* Wq = (const float*)d_in[1];
  const float* Wk = (const float*)d_in[2];
  const float* Wv = (const float*)d_in[3];
  const float* Wp = (const float*)d_in[4];
  float* out = (float*)d_out;
  char* ws = (char*)d_ws;
  const size_t MB = 1024 * 1024;
  // workspace map (peak 124 MB):
  u16* xh   = (u16*)(ws + 0);        // 16MB; reused as O after V-GEMM
  u16* xl   = (u16*)(ws + 16 * MB);  // 16MB
  u16* wqkh = (u16*)(ws + 32 * MB);  // 4MB  [2048][1024]
  u16* wqkl = (u16*)(ws + 36 * MB);  // 4MB
  u16* wvt  = (u16*)(ws + 40 * MB);  // 2MB
  u16* wpt  = (u16*)(ws + 42 * MB);  // 2MB
  u16* Qhf  = (u16*)(ws + 44 * MB);  // 16MB frag-major Q hi
  u16* Qlf  = (u16*)(ws + 60 * MB);  // 16MB frag-major Q lo
  u16* Khf  = (u16*)(ws + 76 * MB);  // 16MB frag-major K hi
  u16* Klf  = (u16*)(ws + 92 * MB);  // 16MB frag-major K lo
  u16* Vf   = (u16*)(ws + 108 * MB); // 16MB frag-major V
  u16* obuf = xh;
  (void)in_sizes; (void)n_in; (void)out_size; (void)ws_size;

  prep_kernel<<<8192, 256, 0, stream>>>(
      x, xh, xl, Wq, Wk, Wv, Wp,
      wqkh, wqkl, wqkh + 1024 * 1024, wqkl + 1024 * 1024, wvt, wpt);
  qkbt_kernel<<<512, 512, 0, stream>>>(xh, xl, wqkh, wqkl,
                                       Qhf, Qlf, Khf, Klf, wvt, Vf);
  attn_kernel<<<512, 256, 0, stream>>>(Qhf, Qlf, Khf, Klf, Vf, obuf);
  gemm_p_kernel<<<dim3(64, 4), 512, 0, stream>>>(obuf, wpt, out);
}